// Round 1
// baseline (843.083 us; speedup 1.0000x reference)
//
#include <hip/hip_runtime.h>

#define DD 192
#define HH 192
#define WW 192
#define NVOX (DD * HH * WW)

__global__ __launch_bounds__(256) void warp_mse_reduce(
    const float* __restrict__ mov,
    const float* __restrict__ vf,
    const float* __restrict__ fix,
    const int* __restrict__ mask,
    float* __restrict__ acc)  // acc[0] = sum(sq*m), acc[1] = sum(m)
{
    const int idx = blockIdx.x * blockDim.x + threadIdx.x;
    float sq = 0.0f, cnt = 0.0f;

    if (idx < NVOX) {
        const int w = idx % WW;
        const int t = idx / WW;
        const int h = t % HH;
        const int d = t / HH;

        const float z = (float)d + vf[idx];
        const float y = (float)h + vf[NVOX + idx];
        const float x = (float)w + vf[2 * NVOX + idx];

        const float z0f = floorf(z), y0f = floorf(y), x0f = floorf(x);
        const float wz = z - z0f, wy = y - y0f, wx = x - x0f;
        const int z0 = (int)z0f, y0 = (int)y0f, x0 = (int)x0f;
        const int z1 = z0 + 1, y1 = y0 + 1, x1 = x0 + 1;

        float v000, v001, v010, v011, v100, v101, v110, v111;

        if (z0 >= 0 && z1 < DD && y0 >= 0 && y1 < HH && x0 >= 0 && x1 < WW) {
            // fast path: whole 2x2x2 cell in-bounds
            const long base = ((long)z0 * HH + y0) * WW + x0;
            v000 = mov[base];
            v001 = mov[base + 1];
            v010 = mov[base + WW];
            v011 = mov[base + WW + 1];
            v100 = mov[base + (long)HH * WW];
            v101 = mov[base + (long)HH * WW + 1];
            v110 = mov[base + (long)HH * WW + WW];
            v111 = mov[base + (long)HH * WW + WW + 1];
        } else {
            const bool zi0 = (z0 >= 0) & (z0 < DD), zi1 = (z1 >= 0) & (z1 < DD);
            const bool yi0 = (y0 >= 0) & (y0 < HH), yi1 = (y1 >= 0) & (y1 < HH);
            const bool xi0 = (x0 >= 0) & (x0 < WW), xi1 = (x1 >= 0) & (x1 < WW);
            auto ld = [&](int iz, int iy, int ix, bool ok) -> float {
                if (!ok) return 0.0f;
                return mov[((long)iz * HH + iy) * WW + ix];
            };
            v000 = ld(z0, y0, x0, zi0 & yi0 & xi0);
            v001 = ld(z0, y0, x1, zi0 & yi0 & xi1);
            v010 = ld(z0, y1, x0, zi0 & yi1 & xi0);
            v011 = ld(z0, y1, x1, zi0 & yi1 & xi1);
            v100 = ld(z1, y0, x0, zi1 & yi0 & xi0);
            v101 = ld(z1, y0, x1, zi1 & yi0 & xi1);
            v110 = ld(z1, y1, x0, zi1 & yi1 & xi0);
            v111 = ld(z1, y1, x1, zi1 & yi1 & xi1);
        }

        const float c00 = v000 + (v001 - v000) * wx;
        const float c01 = v010 + (v011 - v010) * wx;
        const float c10 = v100 + (v101 - v100) * wx;
        const float c11 = v110 + (v111 - v110) * wx;
        const float c0 = c00 + (c01 - c00) * wy;
        const float c1 = c10 + (c11 - c10) * wy;
        const float warped = c0 + (c1 - c0) * wz;

        const float m = (mask[idx] != 0) ? 1.0f : 0.0f;
        const float diff = warped - fix[idx];
        sq = diff * diff * m;
        cnt = m;
    }

    // wave64 shuffle reduction
    #pragma unroll
    for (int off = 32; off > 0; off >>= 1) {
        sq  += __shfl_down(sq, off, 64);
        cnt += __shfl_down(cnt, off, 64);
    }

    __shared__ float s_sq[4], s_cnt[4];
    const int lane = threadIdx.x & 63;
    const int wid = threadIdx.x >> 6;
    if (lane == 0) { s_sq[wid] = sq; s_cnt[wid] = cnt; }
    __syncthreads();

    if (threadIdx.x == 0) {
        float bsq = s_sq[0] + s_sq[1] + s_sq[2] + s_sq[3];
        float bcnt = s_cnt[0] + s_cnt[1] + s_cnt[2] + s_cnt[3];
        atomicAdd(&acc[0], bsq);
        atomicAdd(&acc[1], bcnt);
    }
}

__global__ void warp_mse_finalize(const float* __restrict__ acc, float* __restrict__ out) {
    out[0] = acc[0] / fmaxf(acc[1], 1.0f);
}

extern "C" void kernel_launch(void* const* d_in, const int* in_sizes, int n_in,
                              void* d_out, int out_size, void* d_ws, size_t ws_size,
                              hipStream_t stream) {
    const float* mov  = (const float*)d_in[0];
    const float* vf   = (const float*)d_in[1];
    const float* fix  = (const float*)d_in[2];
    const int*   mask = (const int*)d_in[3];
    float* acc = (float*)d_ws;
    float* out = (float*)d_out;

    hipMemsetAsync(d_ws, 0, 2 * sizeof(float), stream);

    const int block = 256;
    const int grid = (NVOX + block - 1) / block;
    warp_mse_reduce<<<grid, block, 0, stream>>>(mov, vf, fix, mask, acc);
    warp_mse_finalize<<<1, 1, 0, stream>>>(acc, out);
}

// Round 2
// 294.360 us; speedup vs baseline: 2.8641x; 2.8641x over previous
//
#include <hip/hip_runtime.h>

#define DD 192
#define HH 192
#define WW 192
#define NVOX (DD * HH * WW)

#define TS 16                  // tile edge (voxels per block per dim)
#define HL 8                   // halo on each side (+1 upper for z1/y1/x1)
#define RS (TS + 2 * HL + 1)   // 33 — staged region edge
#define RS2 (RS * RS)          // 1089
#define RSIZE (RS * RS * RS)   // 35937 floats = 140.4 KB

__global__ __launch_bounds__(1024) void warp_mse_tiled(
    const float* __restrict__ mov,
    const float* __restrict__ vf,
    const float* __restrict__ fix,
    const int* __restrict__ mask,
    float* __restrict__ acc)  // acc[0]=sum(sq*m), acc[1]=sum(m)
{
    __shared__ float smov[RSIZE];
    __shared__ float s_sq[16], s_cnt[16];

    const int tid = threadIdx.x;
    const int bx0 = blockIdx.x * TS;
    const int by0 = blockIdx.y * TS;
    const int bz0 = blockIdx.z * TS;

    // ---- stage mov region [b*0-HL, b*0-HL+RS) into LDS, zero-padded ----
    // zero padding outside the volume == reference's zero-padding gather,
    // so the fast path needs no per-corner validity checks.
    const int z_lo = bz0 - HL, y_lo = by0 - HL, x_lo = bx0 - HL;
    for (int i = tid; i < RSIZE; i += 1024) {
        const int rz = i / RS2;
        const int rem = i - rz * RS2;
        const int ry = rem / RS;
        const int rx = rem - ry * RS;
        const int gz = z_lo + rz;
        const int gy = y_lo + ry;
        const int gx = x_lo + rx;
        float v = 0.0f;
        if ((unsigned)gz < DD && (unsigned)gy < HH && (unsigned)gx < WW)
            v = mov[(gz * HH + gy) * WW + gx];
        smov[i] = v;
    }
    __syncthreads();

    // ---- compute: each thread handles 4 consecutive-x voxels ----
    const int lxg = (tid & 3) * 4;       // x offset of this thread's quad
    const int ly  = (tid >> 2) & 15;
    const int lz  = tid >> 6;
    const int gz = bz0 + lz;
    const int gy = by0 + ly;
    const int gx0 = bx0 + lxg;
    const int base = (gz * HH + gy) * WW + gx0;

    const float4 dz4 = *(const float4*)(vf + base);
    const float4 dy4 = *(const float4*)(vf + NVOX + base);
    const float4 dx4 = *(const float4*)(vf + 2 * NVOX + base);
    const float4 f4  = *(const float4*)(fix + base);
    const int4   m4  = *(const int4*)(mask + base);

    const float dzv[4] = {dz4.x, dz4.y, dz4.z, dz4.w};
    const float dyv[4] = {dy4.x, dy4.y, dy4.z, dy4.w};
    const float dxv[4] = {dx4.x, dx4.y, dx4.z, dx4.w};
    const float fv[4]  = {f4.x, f4.y, f4.z, f4.w};
    const int   mv[4]  = {m4.x, m4.y, m4.z, m4.w};

    float sq = 0.0f, cnt = 0.0f;

    #pragma unroll
    for (int j = 0; j < 4; ++j) {
        const float z = (float)gz + dzv[j];
        const float y = (float)gy + dyv[j];
        const float x = (float)(gx0 + j) + dxv[j];

        const float z0f = floorf(z), y0f = floorf(y), x0f = floorf(x);
        const float wz = z - z0f, wy = y - y0f, wx = x - x0f;
        const int z0 = (int)z0f, y0 = (int)y0f, x0 = (int)x0f;

        // local coords within the staged region
        const int z0l = z0 - z_lo, y0l = y0 - y_lo, x0l = x0 - x_lo;
        const bool inbox = ((unsigned)z0l < RS - 1) & ((unsigned)y0l < RS - 1) &
                           ((unsigned)x0l < RS - 1);

        float v000, v001, v010, v011, v100, v101, v110, v111;
        if (inbox) {
            const int o = (z0l * RS + y0l) * RS + x0l;
            v000 = smov[o];
            v001 = smov[o + 1];
            v010 = smov[o + RS];
            v011 = smov[o + RS + 1];
            v100 = smov[o + RS2];
            v101 = smov[o + RS2 + 1];
            v110 = smov[o + RS2 + RS];
            v111 = smov[o + RS2 + RS + 1];
        } else {
            // rare (~0.3% of voxels): displacement beyond the halo
            const int z1 = z0 + 1, y1 = y0 + 1, x1 = x0 + 1;
            const bool zi0 = (unsigned)z0 < DD, zi1 = (unsigned)z1 < DD;
            const bool yi0 = (unsigned)y0 < HH, yi1 = (unsigned)y1 < HH;
            const bool xi0 = (unsigned)x0 < WW, xi1 = (unsigned)x1 < WW;
            auto ld = [&](int iz, int iy, int ix, bool ok) -> float {
                return ok ? mov[(iz * HH + iy) * WW + ix] : 0.0f;
            };
            v000 = ld(z0, y0, x0, zi0 & yi0 & xi0);
            v001 = ld(z0, y0, x1, zi0 & yi0 & xi1);
            v010 = ld(z0, y1, x0, zi0 & yi1 & xi0);
            v011 = ld(z0, y1, x1, zi0 & yi1 & xi1);
            v100 = ld(z1, y0, x0, zi1 & yi0 & xi0);
            v101 = ld(z1, y0, x1, zi1 & yi0 & xi1);
            v110 = ld(z1, y1, x0, zi1 & yi1 & xi0);
            v111 = ld(z1, y1, x1, zi1 & yi1 & xi1);
        }

        const float c00 = v000 + (v001 - v000) * wx;
        const float c01 = v010 + (v011 - v010) * wx;
        const float c10 = v100 + (v101 - v100) * wx;
        const float c11 = v110 + (v111 - v110) * wx;
        const float c0 = c00 + (c01 - c00) * wy;
        const float c1 = c10 + (c11 - c10) * wy;
        const float warped = c0 + (c1 - c0) * wz;

        const float m = (mv[j] != 0) ? 1.0f : 0.0f;
        const float diff = warped - fv[j];
        sq += diff * diff * m;
        cnt += m;
    }

    // ---- reduction: wave64 shuffle -> LDS -> one atomic pair per block ----
    #pragma unroll
    for (int off = 32; off > 0; off >>= 1) {
        sq  += __shfl_down(sq, off, 64);
        cnt += __shfl_down(cnt, off, 64);
    }
    const int lane = tid & 63;
    const int wid = tid >> 6;
    if (lane == 0) { s_sq[wid] = sq; s_cnt[wid] = cnt; }
    __syncthreads();
    if (tid == 0) {
        float bsq = 0.0f, bcnt = 0.0f;
        #pragma unroll
        for (int i = 0; i < 16; ++i) { bsq += s_sq[i]; bcnt += s_cnt[i]; }
        atomicAdd(&acc[0], bsq);
        atomicAdd(&acc[1], bcnt);
    }
}

__global__ void warp_mse_finalize(const float* __restrict__ acc, float* __restrict__ out) {
    out[0] = acc[0] / fmaxf(acc[1], 1.0f);
}

extern "C" void kernel_launch(void* const* d_in, const int* in_sizes, int n_in,
                              void* d_out, int out_size, void* d_ws, size_t ws_size,
                              hipStream_t stream) {
    const float* mov  = (const float*)d_in[0];
    const float* vf   = (const float*)d_in[1];
    const float* fix  = (const float*)d_in[2];
    const int*   mask = (const int*)d_in[3];
    float* acc = (float*)d_ws;
    float* out = (float*)d_out;

    hipMemsetAsync(d_ws, 0, 2 * sizeof(float), stream);

    dim3 grid(WW / TS, HH / TS, DD / TS);  // 12 x 12 x 12 = 1728 blocks
    warp_mse_tiled<<<grid, 1024, 0, stream>>>(mov, vf, fix, mask, acc);
    warp_mse_finalize<<<1, 1, 0, stream>>>(acc, out);
}